// Round 3
// baseline (351.462 us; speedup 1.0000x reference)
//
#include <hip/hip_runtime.h>
#include <math.h>

#define NHID  1024
#define NCLS  224
#define NTPC  225
#define BATCH 2048

#define KSPLIT 8                     // K-chunks of 128 rows
#define KCH    128
#define NTILES (BATCH / 16)          // 128 sample-tiles for the top GEMM
#define NBOT_BLOCKS (NCLS * KSPLIT)      // 1792
#define NTOP_BLOCKS (NTILES * KSPLIT)    // 1024

#define YTOPK (BATCH * NCLS)         // floats per top k-slab
#define YBOTK (BATCH * NTPC)         // floats per bottom k-slab

// ws layout (bytes):
#define CLS_OFF  0
#define POS_OFF  8192
#define LIST_OFF 16384
#define OFFS_OFF 24576
#define YTOP_OFF 32768
#define YTOP_BYTES (KSPLIT * YTOPK * 4)
#define YBOT_OFF (YTOP_OFF + YTOP_BYTES)
#define YBOT_BYTES (KSPLIT * YBOTK * 4)

// ---------------------------------------------------------------------------
// Pass 0: label decode (int32/int64 autodetect), class/pos, group-by-class.
// ---------------------------------------------------------------------------
__global__ __launch_bounds__(256) void group_kernel(const int* __restrict__ labels,
                                                    int* __restrict__ cls,
                                                    int* __restrict__ pos,
                                                    int* __restrict__ list,
                                                    int* __restrict__ offs) {
    __shared__ int cnt[NCLS];
    __shared__ int sc[256];
    __shared__ int bex[NCLS];
    __shared__ int nz;
    const int tid = threadIdx.x;
    if (tid == 0) nz = 0;
    for (int j = tid; j < NCLS; j += 256) cnt[j] = 0;
    __syncthreads();
    int loc = 0;
    for (int k = 0; k < 4; ++k) {
        int i = tid + 256 * k;
        if (labels[2 * i + 1] != 0) loc = 1;
    }
    if (loc) atomicOr(&nz, 1);
    __syncthreads();
    const bool is64 = (nz == 0);
    int myc[8], myr[8];
#pragma unroll
    for (int k = 0; k < 8; ++k) {
        int i = tid + 256 * k;
        int l = is64 ? labels[2 * i] : labels[i];
        int c = l / NTPC;
        cls[i] = c;
        pos[i] = l - c * NTPC;
        myc[k] = c;
        myr[k] = atomicAdd(&cnt[c], 1);
    }
    __syncthreads();
    int v = (tid < NCLS) ? cnt[tid] : 0;
    sc[tid] = v;
    __syncthreads();
    for (int off = 1; off < 256; off <<= 1) {
        int u = (tid >= off) ? sc[tid - off] : 0;
        __syncthreads();
        sc[tid] += u;
        __syncthreads();
    }
    if (tid < NCLS) {
        int ex = sc[tid] - v;
        bex[tid] = ex;
        offs[tid] = ex;
    }
    if (tid == 0) offs[NCLS] = BATCH;
    __syncthreads();
#pragma unroll
    for (int k = 0; k < 8; ++k) {
        int i = tid + 256 * k;
        list[bex[myc[k]] + myr[k]] = i;
    }
}

// ---------------------------------------------------------------------------
// Pass 1: K-split partial GEMMs, chunk = 128 rows, KSPLIT = 8, 2816 blocks.
// Round-2 lesson: old decomposition (wave = col-group) made every wave read
// all 128 rows x 4 ds_read_b128 per tile = 2048 broadcast b128/block-tile;
// at ~12cy LDS-return each that is ~113us chip-wide == measured 117us.
// New decomposition: wave w owns SAMPLES 4w..4w+3 and ALL cols (lane l ->
// cols l, l+64, l+128, l+192). Per row: ONE broadcast ds_read_b128 (own
// sample quad) + 4 W dword loads (imm offsets off 2 row ptrs) + 16 FMAs.
// LDS reads drop 4x (512/block-tile, ~28us floor). acc = 16 VGPR.
// W lines shared by the 4 waves through L1/L2 (no extra HBM traffic).
// Outputs: plain coalesced stores into per-k slabs (atomics removed; the
// 7.4M L2 read-modify-writes were ~24us + serialization). finalize sums k.
// Block-index transpose (c = bi % 224, 224 % 8 == 0): chunks of one target
// on the same XCD for L2 locality of x and y.
// ---------------------------------------------------------------------------
template<int YC, bool BOT>
__device__ __forceinline__ void run_tiles(const float* __restrict__ x,
                                          const float* __restrict__ W,
                                          float* __restrict__ yk,
                                          const int* __restrict__ list,
                                          int o, int n, int hbase,
                                          float* __restrict__ xs) {
    const int tid = threadIdx.x;
    const int w = tid >> 6, l = tid & 63;
    const int col3  = 192 + l;
    const int col3c = min(col3, YC - 1);        // clamp keeps loads in-bounds
    const int r  = tid & 127;                   // staging row within chunk
    const int hs = tid >> 7;                    // sample-half (0: i<8, 1: i>=8)
    const int rq = (r >> 1) & 3;                // staging swizzle key
    const float4* xsq = (const float4*)xs;

    for (int tile = 0; tile * 16 < n; ++tile) {
        if (tile) __syncthreads();              // xs reuse vs prior compute reads
        // stage: rows r=tid&127, each thread stages 8 samples of its row.
        // For fixed j a wave's 64 lanes cover 64 consecutive rows -> 256B
        // coalesced loads of x. XOR-quad swizzle: 8-way write conflict
        // (cheap, once per tile); compute reads are broadcast b128.
        const float* xrow = x + hbase + r;
#pragma unroll
        for (int j = 0; j < 8; ++j) {
            const int i = hs * 8 + j;
            const int idx = tile * 16 + i;
            const int s = BOT ? list[o + min(idx, n - 1)] : (o + idx);
            xs[(r << 4) + ((((i >> 2) ^ rq) << 2) | (i & 3))] = xrow[(size_t)s * NHID];
        }
        __syncthreads();

        float acc[16];                          // [sample-in-quad][colgroup]
#pragma unroll
        for (int i = 0; i < 16; ++i) acc[i] = 0.f;

        // g0..g2 cols l/l+64/l+128 are always < 224 <= YC: imm offsets off
        // wA. g3 clamped separately (w3). 8-row groups keep the LDS slot
        // (w ^ ((h>>1)&3)) and all W imm offsets compile-time.
        const float* wA = W + (size_t)hbase * YC + l;
        const float* w3 = W + (size_t)hbase * YC + col3c;

#pragma unroll 1
        for (int h0 = 0; h0 < KCH; h0 += 8) {
            const float* wB  = wA + 4 * YC;
            const float* w3B = w3 + 4 * YC;
#pragma unroll
            for (int j = 0; j < 8; ++j) {
                const float4 xv = xsq[(h0 + j) * 4 + (w ^ (j >> 1))];
                const float* wp  = (j < 4) ? wA : wB;
                const float* w3p = (j < 4) ? w3 : w3B;
                const int jj = j & 3;
                const float w0  = wp[jj * YC];
                const float w1  = wp[jj * YC + 64];
                const float w2  = wp[jj * YC + 128];
                const float w3v = w3p[jj * YC];
                acc[0]  = fmaf(xv.x, w0,  acc[0]);
                acc[1]  = fmaf(xv.x, w1,  acc[1]);
                acc[2]  = fmaf(xv.x, w2,  acc[2]);
                acc[3]  = fmaf(xv.x, w3v, acc[3]);
                acc[4]  = fmaf(xv.y, w0,  acc[4]);
                acc[5]  = fmaf(xv.y, w1,  acc[5]);
                acc[6]  = fmaf(xv.y, w2,  acc[6]);
                acc[7]  = fmaf(xv.y, w3v, acc[7]);
                acc[8]  = fmaf(xv.z, w0,  acc[8]);
                acc[9]  = fmaf(xv.z, w1,  acc[9]);
                acc[10] = fmaf(xv.z, w2,  acc[10]);
                acc[11] = fmaf(xv.z, w3v, acc[11]);
                acc[12] = fmaf(xv.w, w0,  acc[12]);
                acc[13] = fmaf(xv.w, w1,  acc[13]);
                acc[14] = fmaf(xv.w, w2,  acc[14]);
                acc[15] = fmaf(xv.w, w3v, acc[15]);
            }
            wA += 8 * YC;
            w3 += 8 * YC;
        }

        // epilogue: wave w stores its 4 samples, 4 coalesced 256B stores each
        const int nt = min(n - tile * 16, 16);
#pragma unroll
        for (int jj = 0; jj < 4; ++jj) {
            const int it = 4 * w + jj;
            if (it < nt) {
                const int s = BOT ? list[o + tile * 16 + it] : (o + tile * 16 + it);
                float* yr = yk + (size_t)s * YC;
                yr[l]       = acc[jj * 4 + 0];
                yr[l + 64]  = acc[jj * 4 + 1];
                yr[l + 128] = acc[jj * 4 + 2];
                if (col3 < YC) yr[col3] = acc[jj * 4 + 3];
            }
        }
    }
}

__global__ __launch_bounds__(256, 8) void partial_kernel(const float* __restrict__ x,
                                                         const float* __restrict__ Wt,
                                                         const float* __restrict__ Wb,
                                                         const int* __restrict__ list,
                                                         const int* __restrict__ offs,
                                                         float* __restrict__ ytop,
                                                         float* __restrict__ ybot) {
    __shared__ __align__(16) float xs[KCH * 16];   // 8 KB
    const int bi = blockIdx.x;
    if (bi < NBOT_BLOCKS) {
        const int c = bi % NCLS;        // 224 % 8 == 0 -> all chunks of class c
        const int k = bi / NCLS;        // land on XCD (c % 8)
        const int o = offs[c];
        const int n = offs[c + 1] - o;
        run_tiles<NTPC, true>(x, Wb + (size_t)c * (NHID * NTPC),
                              ybot + (size_t)k * YBOTK, list, o, n, k * KCH, xs);
    } else {
        const int b2 = bi - NBOT_BLOCKS;
        const int st = b2 % NTILES;     // 128 % 8 == 0 -> chunks of tile st
        const int k  = b2 / NTILES;     // land on one XCD
        run_tiles<NCLS, false>(x, Wt, ytop + (size_t)k * YTOPK, list,
                               st * 16, 16, k * KCH, xs);
    }
}

// ---------------------------------------------------------------------------
// Pass 2: per-sample k-slab reduction + dual softmax + product. One wave per
// sample. 8 extra coalesced loads per col replace the global atomics.
// ---------------------------------------------------------------------------
__global__ __launch_bounds__(256) void finalize_kernel(const float* __restrict__ ytop,
                                                       const float* __restrict__ ybot,
                                                       const float* __restrict__ bt,
                                                       const float* __restrict__ bb,
                                                       const int* __restrict__ cls,
                                                       const int* __restrict__ pos,
                                                       float* __restrict__ out) {
    const int w = threadIdx.x >> 6, l = threadIdx.x & 63;
    const int s = blockIdx.x * 4 + w;
    const int c = cls[s], p = pos[s];

    float v[4];
#pragma unroll
    for (int g = 0; g < 4; ++g) {
        int col = l + 64 * g;
        if (col < NCLS) {
            float a = bt[col];
#pragma unroll
            for (int k = 0; k < KSPLIT; ++k)
                a += ytop[(size_t)k * YTOPK + (size_t)s * NCLS + col];
            v[g] = a;
        } else {
            v[g] = -INFINITY;
        }
    }
    float mx = fmaxf(fmaxf(v[0], v[1]), fmaxf(v[2], v[3]));
#pragma unroll
    for (int off = 32; off; off >>= 1) mx = fmaxf(mx, __shfl_xor(mx, off));
    float sum = 0.f, tc = 0.f;
#pragma unroll
    for (int g = 0; g < 4; ++g) {
        int col = l + 64 * g;
        float e = (col < NCLS) ? __expf(v[g] - mx) : 0.f;
        sum += e;
        if (col == c) tc = e;
    }
#pragma unroll
    for (int off = 32; off; off >>= 1) {
        sum += __shfl_xor(sum, off);
        tc  += __shfl_xor(tc, off);
    }
    const float tp = tc / sum;

#pragma unroll
    for (int g = 0; g < 4; ++g) {
        int col = l + 64 * g;
        if (col < NTPC) {
            float a = bb[c * NTPC + col];
#pragma unroll
            for (int k = 0; k < KSPLIT; ++k)
                a += ybot[(size_t)k * YBOTK + (size_t)s * NTPC + col];
            v[g] = a;
        } else {
            v[g] = -INFINITY;
        }
    }
    mx = fmaxf(fmaxf(v[0], v[1]), fmaxf(v[2], v[3]));
#pragma unroll
    for (int off = 32; off; off >>= 1) mx = fmaxf(mx, __shfl_xor(mx, off));
    float bsum = 0.f, ep = 0.f;
#pragma unroll
    for (int g = 0; g < 4; ++g) {
        int col = l + 64 * g;
        float e = (col < NTPC) ? __expf(v[g] - mx) : 0.f;
        bsum += e;
        if (col == p) ep = e;
    }
#pragma unroll
    for (int off = 32; off; off >>= 1) bsum += __shfl_xor(bsum, off);
#pragma unroll
    for (int g = 0; g < 4; ++g)
        if (l + 64 * g == p) out[s] = tp * ep / bsum;
}

extern "C" void kernel_launch(void* const* d_in, const int* in_sizes, int n_in,
                              void* d_out, int out_size, void* d_ws, size_t ws_size,
                              hipStream_t stream) {
    const float* inputs = (const float*)d_in[0];
    const int*   labels = (const int*)d_in[1];
    const float* topW   = (const float*)d_in[2];
    const float* topB   = (const float*)d_in[3];
    const float* botW   = (const float*)d_in[4];
    const float* botB   = (const float*)d_in[5];
    float* out = (float*)d_out;

    char* ws   = (char*)d_ws;
    int*   cls = (int*)(ws + CLS_OFF);
    int*   pos = (int*)(ws + POS_OFF);
    int*   lst = (int*)(ws + LIST_OFF);
    int*   off = (int*)(ws + OFFS_OFF);
    float* ytop = (float*)(ws + YTOP_OFF);
    float* ybot = (float*)(ws + YBOT_OFF);

    // no memset: every (k, s, col<YC) slab entry is overwritten by pass 1
    group_kernel<<<1, 256, 0, stream>>>(labels, cls, pos, lst, off);
    partial_kernel<<<NBOT_BLOCKS + NTOP_BLOCKS, 256, 0, stream>>>(
        inputs, topW, botW, lst, off, ytop, ybot);
    finalize_kernel<<<BATCH / 4, 256, 0, stream>>>(ytop, ybot, topB, botB, cls, pos, out);
}

// Round 4
// 333.797 us; speedup vs baseline: 1.0529x; 1.0529x over previous
//
#include <hip/hip_runtime.h>
#include <math.h>

#define NHID  1024
#define NCLS  224
#define NTPC  225
#define BATCH 2048

#define KSPLIT 8                     // K-chunks of 128 rows
#define KCH    128
#define NTILES (BATCH / 16)          // 128 sample-tiles for the top GEMM
#define NBOT_BLOCKS (NCLS * KSPLIT)      // 1792
#define NTOP_BLOCKS (NTILES * KSPLIT)    // 1024

#define YTS 224                      // top slab row stride (== NCLS, 16B-mult)
#define YBS 228                      // bottom slab row stride (padded, 16B-mult)
#define YTOPK (BATCH * YTS)          // floats per top k-slab
#define YBOTK (BATCH * YBS)          // floats per bottom k-slab

// ws layout (bytes):
#define CLS_OFF  0
#define POS_OFF  8192
#define LIST_OFF 16384
#define OFFS_OFF 24576
#define YTOP_OFF 32768
#define YTOP_BYTES (KSPLIT * YTOPK * 4)
#define YBOT_OFF (YTOP_OFF + YTOP_BYTES)
#define YBOT_BYTES (KSPLIT * YBOTK * 4)

// W quad vector with 4-byte alignment: bottom W rows have stride 900 B, so
// 3/4 of rows are only dword-aligned. aligned(4) keeps this legal C; the
// backend still emits global_load_dwordx4 under gfx9 unaligned-access mode
// (worst case it splits into dwords -- slower, never incorrect).
typedef float f4u __attribute__((ext_vector_type(4), aligned(4)));

// ---------------------------------------------------------------------------
// Pass 0: label decode (int32/int64 autodetect), class/pos, group-by-class.
// ---------------------------------------------------------------------------
__global__ __launch_bounds__(256) void group_kernel(const int* __restrict__ labels,
                                                    int* __restrict__ cls,
                                                    int* __restrict__ pos,
                                                    int* __restrict__ list,
                                                    int* __restrict__ offs) {
    __shared__ int cnt[NCLS];
    __shared__ int sc[256];
    __shared__ int bex[NCLS];
    __shared__ int nz;
    const int tid = threadIdx.x;
    if (tid == 0) nz = 0;
    for (int j = tid; j < NCLS; j += 256) cnt[j] = 0;
    __syncthreads();
    int loc = 0;
    for (int k = 0; k < 4; ++k) {
        int i = tid + 256 * k;
        if (labels[2 * i + 1] != 0) loc = 1;
    }
    if (loc) atomicOr(&nz, 1);
    __syncthreads();
    const bool is64 = (nz == 0);
    int myc[8], myr[8];
#pragma unroll
    for (int k = 0; k < 8; ++k) {
        int i = tid + 256 * k;
        int l = is64 ? labels[2 * i] : labels[i];
        int c = l / NTPC;
        cls[i] = c;
        pos[i] = l - c * NTPC;
        myc[k] = c;
        myr[k] = atomicAdd(&cnt[c], 1);
    }
    __syncthreads();
    int v = (tid < NCLS) ? cnt[tid] : 0;
    sc[tid] = v;
    __syncthreads();
    for (int off = 1; off < 256; off <<= 1) {
        int u = (tid >= off) ? sc[tid - off] : 0;
        __syncthreads();
        sc[tid] += u;
        __syncthreads();
    }
    if (tid < NCLS) {
        int ex = sc[tid] - v;
        bex[tid] = ex;
        offs[tid] = ex;
    }
    if (tid == 0) offs[NCLS] = BATCH;
    __syncthreads();
#pragma unroll
    for (int k = 0; k < 8; ++k) {
        int i = tid + 256 * k;
        list[bex[myc[k]] + myr[k]] = i;
    }
}

// ---------------------------------------------------------------------------
// Pass 1: K-split partial GEMMs, chunk = 128 rows, KSPLIT = 8, 2816 blocks.
// Pipe model (per round 0-3 measurements): round 0-2 were LDS-pipe-bound
// (2048 broadcast b128/tile x 12cy == 117us); round 3 cut LDS 4x but paid
// 4x VMEM instrs (2048 dword/tile) + VGPR-32 serialization -> 128us.
// This round: wave w owns samples 4w..4w+3; lane l owns cols 4l..4l+3.
// Per row per wave: 1 broadcast ds_read_b128 (sample quad) + 1 W quad load
// (dwordx4, unaligned-tolerant f4u) + 16 FMAs. 512 VMEM + 512 LDS per tile
// (both ~4x below round 0/3's respective bottleneck counts).
// launch_bounds(256,4): 128-VGPR budget so the explicit wva/wvb ping-pong
// (4-8 rows of W prefetch in flight) survives regalloc -- rounds 1/3 showed
// the compiler otherwise pins VGPR=32 and serializes the stream.
// Outputs: float4 stores into per-k slabs (bottom stride padded to 228 so
// the col-224 tail lane stores a full quad into pad). finalize sums slabs.
// Block-index transpose (c = bi % 224, 224 % 8 == 0): chunks of one target
// on the same XCD for L2 locality of x and y.
// ---------------------------------------------------------------------------
template<int YC, int YS, bool BOT>
__device__ __forceinline__ void run_tiles(const float* __restrict__ x,
                                          const float* __restrict__ W,
                                          float* __restrict__ yk,
                                          const int* __restrict__ list,
                                          int o, int n, int hbase,
                                          float* __restrict__ xs) {
    const int tid = threadIdx.x;
    const int w = tid >> 6, l = tid & 63;
    const int cb  = 4 * l;                      // owned col quad base
    const int cbc = min(cb, YC - 4);            // clamped load base (in-row)
    const int r  = tid & 127;                   // staging row within chunk
    const int hs = tid >> 7;                    // sample-half (0: i<8, 1: i>=8)
    const int rq = (r >> 1) & 3;                // staging swizzle key
    const float4* xsq = (const float4*)xs;

    for (int tile = 0; tile * 16 < n; ++tile) {
        if (tile) __syncthreads();              // xs reuse vs prior compute reads
        // stage: rows r=tid&127, each thread stages 8 samples of its row.
        // For fixed j a wave's 64 lanes cover 64 consecutive rows -> 256B
        // coalesced loads of x. XOR-quad swizzle: 8-way write conflict
        // (cheap, once per tile); compute reads are broadcast b128.
        const float* xrow = x + hbase + r;
#pragma unroll
        for (int j = 0; j < 8; ++j) {
            const int i = hs * 8 + j;
            const int idx = tile * 16 + i;
            const int s = BOT ? list[o + min(idx, n - 1)] : (o + idx);
            xs[(r << 4) + ((((i >> 2) ^ rq) << 2) | (i & 3))] = xrow[(size_t)s * NHID];
        }
        __syncthreads();

        float4 acc[4];                          // [sample-in-quad] x 4 cols
#pragma unroll
        for (int i = 0; i < 4; ++i) acc[i] = make_float4(0.f, 0.f, 0.f, 0.f);

        // 4-row sub-groups; h0 % 8 == 0 keeps the LDS swizzle slot
        // (w ^ (ph + (j>>1))) compile-time per unrolled j.
        auto compute4 = [&](int hb, int ph, const f4u (&wv)[4]) {
#pragma unroll
            for (int j = 0; j < 4; ++j) {
                const float4 xv = xsq[(hb + j) * 4 + (w ^ (ph + (j >> 1)))];
                const f4u wq = wv[j];
                acc[0].x = fmaf(xv.x, wq.x, acc[0].x);
                acc[0].y = fmaf(xv.x, wq.y, acc[0].y);
                acc[0].z = fmaf(xv.x, wq.z, acc[0].z);
                acc[0].w = fmaf(xv.x, wq.w, acc[0].w);
                acc[1].x = fmaf(xv.y, wq.x, acc[1].x);
                acc[1].y = fmaf(xv.y, wq.y, acc[1].y);
                acc[1].z = fmaf(xv.y, wq.z, acc[1].z);
                acc[1].w = fmaf(xv.y, wq.w, acc[1].w);
                acc[2].x = fmaf(xv.z, wq.x, acc[2].x);
                acc[2].y = fmaf(xv.z, wq.y, acc[2].y);
                acc[2].z = fmaf(xv.z, wq.z, acc[2].z);
                acc[2].w = fmaf(xv.z, wq.w, acc[2].w);
                acc[3].x = fmaf(xv.w, wq.x, acc[3].x);
                acc[3].y = fmaf(xv.w, wq.y, acc[3].y);
                acc[3].z = fmaf(xv.w, wq.z, acc[3].z);
                acc[3].w = fmaf(xv.w, wq.w, acc[3].w);
            }
        };

        const float* wp = W + (size_t)hbase * YC + cbc;
        f4u wva[4], wvb[4];
#pragma unroll
        for (int j = 0; j < 4; ++j)
            wva[j] = *(const f4u*)(wp + (size_t)j * YC);

#pragma unroll 1
        for (int h0 = 0; h0 < KCH; h0 += 8) {
            const float* wpb = wp + 4 * (size_t)YC;
#pragma unroll
            for (int j = 0; j < 4; ++j)
                wvb[j] = *(const f4u*)(wpb + (size_t)j * YC);
            compute4(h0, 0, wva);
            // clamp keeps the (dead) final prefetch in-bounds
            const float* wpa = wp + ((h0 + 8 < KCH) ? 8 : 0) * (size_t)YC;
#pragma unroll
            for (int j = 0; j < 4; ++j)
                wva[j] = *(const f4u*)(wpa + (size_t)j * YC);
            compute4(h0 + 4, 2, wvb);
            wp += 8 * (size_t)YC;
        }

        // epilogue: wave w stores its 4 samples as float4 (16B-aligned:
        // YS*4 is a multiple of 16 and cb = 16B*l).
        const int nt = min(n - tile * 16, 16);
#pragma unroll
        for (int jj = 0; jj < 4; ++jj) {
            const int it = 4 * w + jj;
            if (it < nt) {
                const int s = BOT ? list[o + tile * 16 + it] : (o + tile * 16 + it);
                float* yr = yk + (size_t)s * YS;
                if (cb + 3 < YC) {
                    *(float4*)(yr + cb) = acc[jj];
                } else if (cb < YC) {
                    // tail lane (bottom l=56): owns col YC-1 == cbc+3
                    yr[cb] = acc[jj].w;
                }
            }
        }
    }
}

__global__ __launch_bounds__(256, 4) void partial_kernel(const float* __restrict__ x,
                                                         const float* __restrict__ Wt,
                                                         const float* __restrict__ Wb,
                                                         const int* __restrict__ list,
                                                         const int* __restrict__ offs,
                                                         float* __restrict__ ytop,
                                                         float* __restrict__ ybot) {
    __shared__ __align__(16) float xs[KCH * 16];   // 8 KB
    const int bi = blockIdx.x;
    if (bi < NBOT_BLOCKS) {
        const int c = bi % NCLS;        // 224 % 8 == 0 -> all chunks of class c
        const int k = bi / NCLS;        // land on XCD (c % 8)
        const int o = offs[c];
        const int n = offs[c + 1] - o;
        run_tiles<NTPC, YBS, true>(x, Wb + (size_t)c * (NHID * NTPC),
                                   ybot + (size_t)k * YBOTK, list, o, n, k * KCH, xs);
    } else {
        const int b2 = bi - NBOT_BLOCKS;
        const int st = b2 % NTILES;     // 128 % 8 == 0 -> chunks of tile st
        const int k  = b2 / NTILES;     // land on one XCD
        run_tiles<NCLS, YTS, false>(x, Wt, ytop + (size_t)k * YTOPK, list,
                                    st * 16, 16, k * KCH, xs);
    }
}

// ---------------------------------------------------------------------------
// Pass 2: per-sample k-slab reduction + dual softmax + product. One wave per
// sample. Bottom slabs have padded row stride YBS.
// ---------------------------------------------------------------------------
__global__ __launch_bounds__(256) void finalize_kernel(const float* __restrict__ ytop,
                                                       const float* __restrict__ ybot,
                                                       const float* __restrict__ bt,
                                                       const float* __restrict__ bb,
                                                       const int* __restrict__ cls,
                                                       const int* __restrict__ pos,
                                                       float* __restrict__ out) {
    const int w = threadIdx.x >> 6, l = threadIdx.x & 63;
    const int s = blockIdx.x * 4 + w;
    const int c = cls[s], p = pos[s];

    float v[4];
#pragma unroll
    for (int g = 0; g < 4; ++g) {
        int col = l + 64 * g;
        if (col < NCLS) {
            float a = bt[col];
#pragma unroll
            for (int k = 0; k < KSPLIT; ++k)
                a += ytop[(size_t)k * YTOPK + (size_t)s * YTS + col];
            v[g] = a;
        } else {
            v[g] = -INFINITY;
        }
    }
    float mx = fmaxf(fmaxf(v[0], v[1]), fmaxf(v[2], v[3]));
#pragma unroll
    for (int off = 32; off; off >>= 1) mx = fmaxf(mx, __shfl_xor(mx, off));
    float sum = 0.f, tc = 0.f;
#pragma unroll
    for (int g = 0; g < 4; ++g) {
        int col = l + 64 * g;
        float e = (col < NCLS) ? __expf(v[g] - mx) : 0.f;
        sum += e;
        if (col == c) tc = e;
    }
#pragma unroll
    for (int off = 32; off; off >>= 1) {
        sum += __shfl_xor(sum, off);
        tc  += __shfl_xor(tc, off);
    }
    const float tp = tc / sum;

#pragma unroll
    for (int g = 0; g < 4; ++g) {
        int col = l + 64 * g;
        if (col < NTPC) {
            float a = bb[c * NTPC + col];
#pragma unroll
            for (int k = 0; k < KSPLIT; ++k)
                a += ybot[(size_t)k * YBOTK + (size_t)s * YBS + col];
            v[g] = a;
        } else {
            v[g] = -INFINITY;
        }
    }
    mx = fmaxf(fmaxf(v[0], v[1]), fmaxf(v[2], v[3]));
#pragma unroll
    for (int off = 32; off; off >>= 1) mx = fmaxf(mx, __shfl_xor(mx, off));
    float bsum = 0.f, ep = 0.f;
#pragma unroll
    for (int g = 0; g < 4; ++g) {
        int col = l + 64 * g;
        float e = (col < NTPC) ? __expf(v[g] - mx) : 0.f;
        bsum += e;
        if (col == p) ep = e;
    }
#pragma unroll
    for (int off = 32; off; off >>= 1) bsum += __shfl_xor(bsum, off);
#pragma unroll
    for (int g = 0; g < 4; ++g)
        if (l + 64 * g == p) out[s] = tp * ep / bsum;
}

extern "C" void kernel_launch(void* const* d_in, const int* in_sizes, int n_in,
                              void* d_out, int out_size, void* d_ws, size_t ws_size,
                              hipStream_t stream) {
    const float* inputs = (const float*)d_in[0];
    const int*   labels = (const int*)d_in[1];
    const float* topW   = (const float*)d_in[2];
    const float* topB   = (const float*)d_in[3];
    const float* botW   = (const float*)d_in[4];
    const float* botB   = (const float*)d_in[5];
    float* out = (float*)d_out;

    char* ws   = (char*)d_ws;
    int*   cls = (int*)(ws + CLS_OFF);
    int*   pos = (int*)(ws + POS_OFF);
    int*   lst = (int*)(ws + LIST_OFF);
    int*   off = (int*)(ws + OFFS_OFF);
    float* ytop = (float*)(ws + YTOP_OFF);
    float* ybot = (float*)(ws + YBOT_OFF);

    // no memset: every slab entry read by finalize is overwritten by pass 1
    group_kernel<<<1, 256, 0, stream>>>(labels, cls, pos, lst, off);
    partial_kernel<<<NBOT_BLOCKS + NTOP_BLOCKS, 256, 0, stream>>>(
        inputs, topW, botW, lst, off, ytop, ybot);
    finalize_kernel<<<BATCH / 4, 256, 0, stream>>>(ytop, ybot, topB, botB, cls, pos, out);
}